// Round 8
// baseline (38.921 us; speedup 1.0000x reference)
//
#include <hip/hip_runtime.h>

// DCN cross layers, fused closed form — TWO-PASS decomposition.
// out[r,d] = x[r,d] * (1 + sum_i s_i * W[i,d]) + bsum[d]
// s_0 = T = sum_d x[r,d];  s_i = s_{i-1} * (1 + A_{i-1}) + B_{i-1}
// A_j = dot(x_r, W[j]),  B_j = sum_d b[j,d],  bsum[d] = sum_j b[j,d]
//
// K1: read-only pass computes s[r][0..3] -> d_ws (128 KiB). Pure read
//     stream (no competing stores), leaves x L3-resident.
// K2: pure streaming epilogue, ZERO barriers/LDS/reductions. x from L3,
//     write-bound.
// Fallback: monolithic R4 kernel if ws_size < table size.

typedef float v4 __attribute__((ext_vector_type(4)));

constexpr int Bn = 8192;
constexpr int D = 2048;
constexpr int L = 4;
constexpr int THREADS = 256;
constexpr int VEC = 4;
constexpr int PASSES = D / (THREADS * VEC); // 2
constexpr int RPB = 8;                      // rows per block (both passes)
constexpr int GRID = Bn / RPB;              // 1024 = 4 blocks/CU

__device__ inline float hsum(v4 v) { return v.x + v.y + v.z + v.w; }

template <int CTRL>
__device__ inline float dpp_add(float x) {
    int xi = __builtin_bit_cast(int, x);
    int yi = __builtin_amdgcn_update_dpp(0, xi, CTRL, 0xf, 0xf, true);
    return x + __builtin_bit_cast(float, yi);
}
// Full 64-lane sum; result valid in lane 63.
__device__ inline float wave_sum(float x) {
    x = dpp_add<0x111>(x);
    x = dpp_add<0x112>(x);
    x = dpp_add<0x114>(x);
    x = dpp_add<0x118>(x);
    x = dpp_add<0x142>(x);
    x = dpp_add<0x143>(x);
    return x;
}

// ---------------- K1: per-row scalars (read-only stream) ----------------
__global__ __launch_bounds__(THREADS) void scalars_kernel(
    const float* __restrict__ x,
    const float* __restrict__ W,
    const float* __restrict__ b,
    float* __restrict__ stab)   // [Bn][4]
{
    const int tid = threadIdx.x;
    const int lane = tid & 63;
    const int wid = tid >> 6;
    const int col = tid * VEC;

    __shared__ float redp[4][3];
    __shared__ float red[2][4][4];

    v4 xv[PASSES], xn[PASSES];
    {
        const float* xr = x + (size_t)blockIdx.x * D;
#pragma unroll
        for (int p = 0; p < PASSES; ++p)
            xv[p] = *reinterpret_cast<const v4*>(xr + p * (THREADS * VEC) + col);
    }

    // prologue: W0..W2 and B_0..B_2 (only these enter the recurrence)
    v4 wv[3][PASSES];
    float bred[3] = {0.f, 0.f, 0.f};
#pragma unroll
    for (int p = 0; p < PASSES; ++p) {
        const int d = p * (THREADS * VEC) + col;
#pragma unroll
        for (int i = 0; i < 3; ++i) {
            wv[i][p] = *reinterpret_cast<const v4*>(W + i * D + d);
            bred[i] += hsum(*reinterpret_cast<const v4*>(b + i * D + d));
        }
    }
#pragma unroll
    for (int k = 0; k < 3; ++k) bred[k] = wave_sum(bred[k]);
    if (lane == 63)
#pragma unroll
        for (int k = 0; k < 3; ++k) redp[wid][k] = bred[k];
    __syncthreads();
    float Bsc[3];
#pragma unroll
    for (int k = 0; k < 3; ++k)
        Bsc[k] = redp[0][k] + redp[1][k] + redp[2][k] + redp[3][k];

#pragma unroll
    for (int k = 0; k < RPB; ++k) {
        if (k + 1 < RPB) {
            const float* xr = x + (size_t)(blockIdx.x + GRID * (k + 1)) * D;
#pragma unroll
            for (int p = 0; p < PASSES; ++p)
                xn[p] = *reinterpret_cast<const v4*>(xr + p * (THREADS * VEC) + col);
        }

        float sm[4] = {0.f, 0.f, 0.f, 0.f};
#pragma unroll
        for (int p = 0; p < PASSES; ++p) {
            sm[0] += hsum(xv[p]);
#pragma unroll
            for (int i = 0; i < 3; ++i)
                sm[1 + i] += hsum(xv[p] * wv[i][p]);
        }
#pragma unroll
        for (int q = 0; q < 4; ++q) sm[q] = wave_sum(sm[q]);

        if (lane == 63)
#pragma unroll
            for (int q = 0; q < 4; ++q) red[k & 1][wid][q] = sm[q];
        __syncthreads();

        if (tid == 0) {
            const float T = red[k & 1][0][0] + red[k & 1][1][0]
                          + red[k & 1][2][0] + red[k & 1][3][0];
            float A[3];
#pragma unroll
            for (int q = 0; q < 3; ++q)
                A[q] = red[k & 1][0][1 + q] + red[k & 1][1][1 + q]
                     + red[k & 1][2][1 + q] + red[k & 1][3][1 + q];
            v4 s;
            s.x = T;
            s.y = s.x * (1.f + A[0]) + Bsc[0];
            s.z = s.y * (1.f + A[1]) + Bsc[1];
            s.w = s.z * (1.f + A[2]) + Bsc[2];
            *reinterpret_cast<v4*>(stab + ((size_t)blockIdx.x + GRID * k) * 4) = s;
        }

#pragma unroll
        for (int p = 0; p < PASSES; ++p) xv[p] = xn[p];
    }
}

// ---------------- K2: pure streaming epilogue (no sync at all) ----------------
__global__ __launch_bounds__(THREADS) void stream_kernel(
    const float* __restrict__ x,
    const float* __restrict__ W,
    const float* __restrict__ b,
    const float* __restrict__ stab,
    float* __restrict__ out)
{
    const int tid = threadIdx.x;
    const int col = tid * VEC;

    v4 xv[PASSES], xn[PASSES];
    {
        const float* xr = x + (size_t)blockIdx.x * D;
#pragma unroll
        for (int p = 0; p < PASSES; ++p)
            xv[p] = *reinterpret_cast<const v4*>(xr + p * (THREADS * VEC) + col);
    }
    v4 sv = *reinterpret_cast<const v4*>(stab + (size_t)blockIdx.x * 4);

    // prologue: all of W, elementwise bsum (no reduction needed)
    v4 wv[L][PASSES];
    v4 bs[PASSES];
#pragma unroll
    for (int p = 0; p < PASSES; ++p) {
        const int d = p * (THREADS * VEC) + col;
        v4 bsum = {0.f, 0.f, 0.f, 0.f};
#pragma unroll
        for (int i = 0; i < L; ++i) {
            wv[i][p] = *reinterpret_cast<const v4*>(W + i * D + d);
            bsum += *reinterpret_cast<const v4*>(b + i * D + d);
        }
        bs[p] = bsum;
    }

#pragma unroll
    for (int k = 0; k < RPB; ++k) {
        v4 sn;
        if (k + 1 < RPB) {
            const float* xr = x + (size_t)(blockIdx.x + GRID * (k + 1)) * D;
#pragma unroll
            for (int p = 0; p < PASSES; ++p)
                xn[p] = *reinterpret_cast<const v4*>(xr + p * (THREADS * VEC) + col);
            sn = *reinterpret_cast<const v4*>(stab + ((size_t)blockIdx.x + GRID * (k + 1)) * 4);
        }

        float* outr = out + ((size_t)blockIdx.x + GRID * k) * D;
#pragma unroll
        for (int p = 0; p < PASSES; ++p) {
            v4 c = {1.f, 1.f, 1.f, 1.f};
            c += sv.x * wv[0][p];
            c += sv.y * wv[1][p];
            c += sv.z * wv[2][p];
            c += sv.w * wv[3][p];
            *reinterpret_cast<v4*>(outr + p * (THREADS * VEC) + col)
                = xv[p] * c + bs[p];
        }

#pragma unroll
        for (int p = 0; p < PASSES; ++p) xv[p] = xn[p];
        sv = sn;
    }
}

// ---------------- Fallback: monolithic R4 kernel (ws too small) ----------------
__global__ __launch_bounds__(THREADS) void cross_layer_fused(
    const float* __restrict__ x,
    const float* __restrict__ W,
    const float* __restrict__ b,
    float* __restrict__ out)
{
    const int tid = threadIdx.x;
    const int lane = tid & 63;
    const int wid = tid >> 6;
    const int col = tid * VEC;

    __shared__ float redp[4][3];
    __shared__ float red[2][4][4];

    v4 xv[PASSES], xn[PASSES];
    {
        const float* xr = x + (size_t)blockIdx.x * D;
#pragma unroll
        for (int p = 0; p < PASSES; ++p)
            xv[p] = *reinterpret_cast<const v4*>(xr + p * (THREADS * VEC) + col);
    }

    v4 wv[L][PASSES];
    v4 bs[PASSES];
    float bred[3] = {0.f, 0.f, 0.f};
#pragma unroll
    for (int p = 0; p < PASSES; ++p) {
        const int d = p * (THREADS * VEC) + col;
        v4 bsum = {0.f, 0.f, 0.f, 0.f};
#pragma unroll
        for (int i = 0; i < L; ++i) {
            wv[i][p] = *reinterpret_cast<const v4*>(W + i * D + d);
            v4 bb = *reinterpret_cast<const v4*>(b + i * D + d);
            bsum += bb;
            if (i < 3) bred[i] += hsum(bb);
        }
        bs[p] = bsum;
    }
#pragma unroll
    for (int k = 0; k < 3; ++k) bred[k] = wave_sum(bred[k]);
    if (lane == 63)
#pragma unroll
        for (int k = 0; k < 3; ++k) redp[wid][k] = bred[k];
    __syncthreads();
    float Bsc[3];
#pragma unroll
    for (int k = 0; k < 3; ++k)
        Bsc[k] = redp[0][k] + redp[1][k] + redp[2][k] + redp[3][k];

#pragma unroll
    for (int k = 0; k < RPB; ++k) {
        if (k + 1 < RPB) {
            const float* xr = x + (size_t)(blockIdx.x + GRID * (k + 1)) * D;
#pragma unroll
            for (int p = 0; p < PASSES; ++p)
                xn[p] = *reinterpret_cast<const v4*>(xr + p * (THREADS * VEC) + col);
        }

        float sm[4] = {0.f, 0.f, 0.f, 0.f};
#pragma unroll
        for (int p = 0; p < PASSES; ++p) {
            sm[0] += hsum(xv[p]);
#pragma unroll
            for (int i = 0; i < 3; ++i)
                sm[1 + i] += hsum(xv[p] * wv[i][p]);
        }
#pragma unroll
        for (int q = 0; q < 4; ++q) sm[q] = wave_sum(sm[q]);

        if (lane == 63)
#pragma unroll
            for (int q = 0; q < 4; ++q) red[k & 1][wid][q] = sm[q];
        __syncthreads();

        const float T = red[k & 1][0][0] + red[k & 1][1][0]
                      + red[k & 1][2][0] + red[k & 1][3][0];
        float A[3];
#pragma unroll
        for (int q = 0; q < 3; ++q)
            A[q] = red[k & 1][0][1 + q] + red[k & 1][1][1 + q]
                 + red[k & 1][2][1 + q] + red[k & 1][3][1 + q];

        float s[L];
        s[0] = T;
#pragma unroll
        for (int i = 1; i < L; ++i)
            s[i] = s[i - 1] * (1.f + A[i - 1]) + Bsc[i - 1];

        float* outr = out + ((size_t)blockIdx.x + GRID * k) * D;
#pragma unroll
        for (int p = 0; p < PASSES; ++p) {
            v4 c = {1.f, 1.f, 1.f, 1.f};
#pragma unroll
            for (int i = 0; i < L; ++i)
                c += s[i] * wv[i][p];
            *reinterpret_cast<v4*>(outr + p * (THREADS * VEC) + col)
                = xv[p] * c + bs[p];
        }

#pragma unroll
        for (int p = 0; p < PASSES; ++p) xv[p] = xn[p];
    }
}

extern "C" void kernel_launch(void* const* d_in, const int* in_sizes, int n_in,
                              void* d_out, int out_size, void* d_ws, size_t ws_size,
                              hipStream_t stream) {
    const float* x = (const float*)d_in[0];
    const float* W = (const float*)d_in[1];
    const float* b = (const float*)d_in[2];
    float* out = (float*)d_out;

    const size_t table_bytes = (size_t)Bn * 4 * sizeof(float);
    if (ws_size >= table_bytes) {
        float* stab = (float*)d_ws;
        scalars_kernel<<<GRID, THREADS, 0, stream>>>(x, W, b, stab);
        stream_kernel<<<GRID, THREADS, 0, stream>>>(x, W, b, stab, out);
    } else {
        cross_layer_fused<<<GRID, THREADS, 0, stream>>>(x, W, b, out);
    }
}

// Round 9
// 26.600 us; speedup vs baseline: 1.4632x; 1.4632x over previous
//
#include <hip/hip_runtime.h>

// DCN cross layers, fused closed form, persistent blocks. BEST (R4, 26.4us).
// out[r,d] = x[r,d] * (1 + sum_i s_i * W[i,d]) + bsum[d]
// s_0 = T = sum_d x[r,d];  s_i = s_{i-1} * (1 + A_{i-1}) + B_{i-1}
// A_j = dot(x_r, W[j]),  B_j = sum_d b[j,d],  bsum[d] = sum_j b[j,d]
//
// Ledger (what was tried and measured):
//   R1 one-shot per-row blocks .................. 38.2 us
//   R2 persistent RPB=4, W/b in regs ............ 27.9 us
//   R3 +nt loads/stores, RPI=2 .................. 30.3 us (nt killed x L3 residency)
//   R4 RPB=8, cached, 1 barrier/row ............. 26.4 us  <-- BEST (this file)
//   R5 RPI=2 cached ............................. 27.1 us (more in-flight: null)
//   R6 nt-stores only ........................... 27.2 us (L3 contention: null)
//   R7 DPP reduce instead of shuffle ............ 26.4 us (DS-pipe chain: null)
//   R8 two-pass decoupled ....................... 38.9 us (re-read of x dominates)
// => 5.1 TB/s logical mixed stream = 81% of D2D copy ceiling; memory-bound.

typedef float v4 __attribute__((ext_vector_type(4)));

constexpr int Bn = 8192;
constexpr int D = 2048;
constexpr int L = 4;
constexpr int THREADS = 256;
constexpr int VEC = 4;
constexpr int PASSES = D / (THREADS * VEC); // 2
constexpr int RPB = 8;                      // rows per block
constexpr int GRID = Bn / RPB;              // 1024 = 4 blocks/CU

__device__ inline float hsum(v4 v) { return v.x + v.y + v.z + v.w; }

__global__ __launch_bounds__(THREADS) void cross_layer_kernel(
    const float* __restrict__ x,
    const float* __restrict__ W,
    const float* __restrict__ b,
    float* __restrict__ out)
{
    const int tid = threadIdx.x;
    const int lane = tid & 63;
    const int wid = tid >> 6;
    const int col = tid * VEC;

    __shared__ float redp[4][3];     // prologue: B_0..B_2 partials
    __shared__ float red[2][4][4];   // per-row: {T,A0,A1,A2}, double-buffered

    // ---- issue row-0 x loads FIRST so the HBM stream starts immediately ----
    v4 xv[PASSES], xn[PASSES];
    {
        const float* xr = x + (size_t)blockIdx.x * D;
#pragma unroll
        for (int p = 0; p < PASSES; ++p)
            xv[p] = *reinterpret_cast<const v4*>(xr + p * (THREADS * VEC) + col);
    }

    // ---- prologue: block-invariant W and b (L2-hot cached loads) ----
    v4 wv[L][PASSES];
    v4 bs[PASSES];
    float bred[3] = {0.f, 0.f, 0.f};

#pragma unroll
    for (int p = 0; p < PASSES; ++p) {
        const int d = p * (THREADS * VEC) + col;
        v4 bsum = {0.f, 0.f, 0.f, 0.f};
#pragma unroll
        for (int i = 0; i < L; ++i) {
            wv[i][p] = *reinterpret_cast<const v4*>(W + i * D + d);
            v4 bb = *reinterpret_cast<const v4*>(b + i * D + d);
            bsum += bb;
            if (i < 3) bred[i] += hsum(bb);
        }
        bs[p] = bsum;
    }

#pragma unroll
    for (int k = 0; k < 3; ++k)
#pragma unroll
        for (int off = 32; off > 0; off >>= 1)
            bred[k] += __shfl_down(bred[k], off, 64);
    if (lane == 0)
#pragma unroll
        for (int k = 0; k < 3; ++k) redp[wid][k] = bred[k];
    __syncthreads();
    float Bsc[3];
#pragma unroll
    for (int k = 0; k < 3; ++k)
        Bsc[k] = redp[0][k] + redp[1][k] + redp[2][k] + redp[3][k];

    // ---- row loop: 1 row per iteration, prefetch next row ----
#pragma unroll
    for (int k = 0; k < RPB; ++k) {
        if (k + 1 < RPB) {
            const float* xr = x + (size_t)(blockIdx.x + GRID * (k + 1)) * D;
#pragma unroll
            for (int p = 0; p < PASSES; ++p)
                xn[p] = *reinterpret_cast<const v4*>(xr + p * (THREADS * VEC) + col);
        }

        // 4 row sums: T, A0, A1, A2
        float sm[4] = {0.f, 0.f, 0.f, 0.f};
#pragma unroll
        for (int p = 0; p < PASSES; ++p) {
            sm[0] += hsum(xv[p]);
#pragma unroll
            for (int i = 0; i < 3; ++i)
                sm[1 + i] += hsum(xv[p] * wv[i][p]);
        }
#pragma unroll
        for (int q = 0; q < 4; ++q)
#pragma unroll
            for (int off = 32; off > 0; off >>= 1)
                sm[q] += __shfl_down(sm[q], off, 64);

        if (lane == 0)
#pragma unroll
            for (int q = 0; q < 4; ++q) red[k & 1][wid][q] = sm[q];
        __syncthreads();
        // WAR-safe single barrier: reads of red[k&1] happen before the next
        // barrier; this buffer is only rewritten after that barrier.

        const float T = red[k & 1][0][0] + red[k & 1][1][0]
                      + red[k & 1][2][0] + red[k & 1][3][0];
        float A[3];
#pragma unroll
        for (int q = 0; q < 3; ++q)
            A[q] = red[k & 1][0][1 + q] + red[k & 1][1][1 + q]
                 + red[k & 1][2][1 + q] + red[k & 1][3][1 + q];

        float s[L];
        s[0] = T;
#pragma unroll
        for (int i = 1; i < L; ++i)
            s[i] = s[i - 1] * (1.f + A[i - 1]) + Bsc[i - 1];

        float* outr = out + (size_t)(blockIdx.x + GRID * k) * D;
#pragma unroll
        for (int p = 0; p < PASSES; ++p) {
            v4 c = {1.f, 1.f, 1.f, 1.f};
#pragma unroll
            for (int i = 0; i < L; ++i)
                c += s[i] * wv[i][p];
            *reinterpret_cast<v4*>(outr + p * (THREADS * VEC) + col)
                = xv[p] * c + bs[p];
        }

#pragma unroll
        for (int p = 0; p < PASSES; ++p) xv[p] = xn[p];
    }
}

extern "C" void kernel_launch(void* const* d_in, const int* in_sizes, int n_in,
                              void* d_out, int out_size, void* d_ws, size_t ws_size,
                              hipStream_t stream) {
    const float* x = (const float*)d_in[0];
    const float* W = (const float*)d_in[1];
    const float* b = (const float*)d_in[2];
    float* out = (float*)d_out;
    cross_layer_kernel<<<GRID, THREADS, 0, stream>>>(x, W, b, out);
}